// Round 23
// baseline (913.921 us; speedup 1.0000x reference)
//
#include <hip/hip_runtime.h>
#include <hip/hip_bf16.h>

typedef __attribute__((ext_vector_type(8))) short bf16x8;
typedef __attribute__((ext_vector_type(4))) float f32x4;
typedef __attribute__((ext_vector_type(4))) unsigned u32x4;

#define EPSV 1e-5f
#define NN 50000
#define NE 800000
#define NG 64
#define SEGB 1000
#define MFMA16(a, b, c) __builtin_amdgcn_mfma_f32_16x16x32_bf16(a, b, c, 0, 0, 0)

__device__ __forceinline__ unsigned short f2bf(float f) {
  __hip_bfloat16 h = __float2bfloat16(f);   // HW RNE convert on gfx950
  union { __hip_bfloat16 b; unsigned short u; } v; v.b = h;
  return v.u;
}
__device__ __forceinline__ float bf2f(unsigned short h) {
  union { unsigned u; float f; } v; v.u = ((unsigned)h) << 16;
  return v.f;
}
__device__ __forceinline__ float bflo(unsigned u) {
  union { unsigned x; float f; } v; v.x = u << 16; return v.f;
}
__device__ __forceinline__ float bfhi(unsigned u) {
  union { unsigned x; float f; } v; v.x = u & 0xffff0000u; return v.f;
}

// ---------------- conversion + edge-histogram (fused) ----------------

__global__ __launch_bounds__(256) void cvt_pre_kernel(
    const float* __restrict__ x, unsigned short* __restrict__ xb,
    const int* __restrict__ rowIdx, const int* __restrict__ colIdx,
    int* __restrict__ cnt_r, int* __restrict__ cnt_s) {
  const int NX4 = (NN * 128) / 4;   // 1,600,000 >= NE
  for (int idx = blockIdx.x * 256 + threadIdx.x; idx < NX4;
       idx += gridDim.x * 256) {
    float4 v = ((const float4*)x)[idx];
    ushort4 o;
    o.x = f2bf(v.x); o.y = f2bf(v.y); o.z = f2bf(v.z); o.w = f2bf(v.w);
    ((ushort4*)xb)[idx] = o;
    if (idx < NE) {
      atomicAdd(&cnt_r[colIdx[idx]], 1);
      atomicAdd(&cnt_s[rowIdx[idx]], 1);
    }
  }
}

__global__ __launch_bounds__(256) void cvt_small_kernel(
    const float* __restrict__ u,
    const float* __restrict__ eW1, const float* __restrict__ eW2,
    const float* __restrict__ nW1, const float* __restrict__ nW2,
    unsigned short* __restrict__ ub,
    unsigned short* __restrict__ W1eT, unsigned short* __restrict__ WpqT,
    unsigned short* __restrict__ eW2T,
    unsigned short* __restrict__ nW1T, unsigned short* __restrict__ nW2T,
    float* __restrict__ Rg) {
  int i = blockIdx.x * 256 + threadIdx.x;
  const int R0 = NG * 32;
  const int R1 = R0 + 128 * 32;
  const int R2 = R1 + 256 * 128;
  const int R3 = R2 + 128 * 128;
  const int R4 = R3 + 128 * 320;
  const int R5 = R4 + 128 * 128;
  const int R6 = R5 + NG * 128;
  if (i < R0) {
    ub[i] = f2bf(u[i]);
  } else if (i < R1) {
    int j = i - R0; int n = j >> 5, k = j & 31;
    W1eT[j] = f2bf(eW1[k * 128 + n]);
  } else if (i < R2) {
    int j = i - R1; int n = j >> 7, k = j & 127;
    WpqT[j] = (n < 128) ? f2bf(eW1[(32 + k) * 128 + n])
                        : f2bf(eW1[(160 + k) * 128 + (n - 128)]);
  } else if (i < R3) {
    int j = i - R2; int n = j >> 7, k = j & 127;
    eW2T[j] = f2bf(eW2[k * 128 + n]);
  } else if (i < R4) {
    int j = i - R3; int n = j / 320, k = j % 320;
    nW1T[j] = (k < 288) ? f2bf(nW1[k * 128 + n]) : (unsigned short)0;
  } else if (i < R5) {
    int j = i - R4; int n = j >> 7, k = j & 127;
    nW2T[j] = f2bf(nW2[k * 128 + n]);
  } else if (i < R6) {
    int j = i - R5; int g = j >> 7, n = j & 127;
    float s = 0.f;
#pragma unroll
    for (int k = 0; k < 32; ++k) s += u[g * 32 + k] * eW1[(288 + k) * 128 + n];
    Rg[j] = s;
  }
}

// ---------------- PQ precompute ----------------
__global__ __launch_bounds__(256, 2) void pq_kernel(
    const unsigned short* __restrict__ xb,
    const unsigned short* __restrict__ WpqT,
    unsigned short* __restrict__ PQ) {
  __shared__ __align__(16) unsigned short Asm[64][136];
  __shared__ __align__(16) unsigned short Bsm[256][72];
  const int tid = threadIdx.x;
  {
    const int r = tid >> 2, q = tid & 3;
    const int grow = blockIdx.x * 64 + r;
    const uint4 zero = {0u, 0u, 0u, 0u};
    if (grow < NN) {
      const uint4* xs = (const uint4*)(xb + (size_t)grow * 128 + q * 32);
#pragma unroll
      for (int k = 0; k < 4; ++k) *(uint4*)&Asm[r][q * 32 + k * 8] = xs[k];
    } else {
#pragma unroll
      for (int k = 0; k < 4; ++k) *(uint4*)&Asm[r][q * 32 + k * 8] = zero;
    }
  }
  const int w = tid >> 6, lane = tid & 63;
  const int l15 = lane & 15, lg = lane >> 4;
  f32x4 acc[16];
#pragma unroll
  for (int ni = 0; ni < 16; ++ni) acc[ni] = f32x4{0.f, 0.f, 0.f, 0.f};
  for (int kc = 0; kc < 2; ++kc) {
    {
      const uint4* src = (const uint4*)(WpqT + (size_t)tid * 128 + kc * 64);
#pragma unroll
      for (int k = 0; k < 8; ++k) *(uint4*)&Bsm[tid][k * 8] = src[k];
    }
    __syncthreads();
    bf16x8 a0 = *(bf16x8*)&Asm[w * 16 + l15][kc * 64 + lg * 8];
    bf16x8 a1 = *(bf16x8*)&Asm[w * 16 + l15][kc * 64 + 32 + lg * 8];
#pragma unroll
    for (int ni = 0; ni < 16; ++ni) {
      bf16x8 b0 = *(bf16x8*)&Bsm[ni * 16 + l15][lg * 8];
      bf16x8 b1 = *(bf16x8*)&Bsm[ni * 16 + l15][32 + lg * 8];
      acc[ni] = MFMA16(a0, b0, acc[ni]);
      acc[ni] = MFMA16(a1, b1, acc[ni]);
    }
    __syncthreads();
  }
  unsigned short (*Cl)[264] = (unsigned short(*)[264])&Bsm[0][0];
#pragma unroll
  for (int ni = 0; ni < 16; ++ni)
#pragma unroll
    for (int reg = 0; reg < 4; ++reg)
      Cl[w * 16 + lg * 4 + reg][l15 + ni * 16] = f2bf(acc[ni][reg]);
  __syncthreads();
  {
    const int r = tid >> 2, q = tid & 3;
    const int grow = blockIdx.x * 64 + r;
    if (grow < NN) {
#pragma unroll
      for (int k = 0; k < 8; ++k)
        *(uint4*)(PQ + (size_t)grow * 256 + q * 64 + k * 8) =
            *(uint4*)&Cl[r][q * 64 + k * 8];
    }
  }
}

// ---------------- CSR construction ----------------

__global__ __launch_bounds__(1024) void scan2_kernel(
    const int* __restrict__ cnt_r, int* __restrict__ offs_r, int* __restrict__ cur_r,
    const int* __restrict__ cnt_s, int* __restrict__ offs_s, int* __restrict__ cur_s) {
  __shared__ int sums[1024];
  const int* cnt = blockIdx.x ? cnt_s : cnt_r;
  int* offs = blockIdx.x ? offs_s : offs_r;
  int* cur  = blockIdx.x ? cur_s : cur_r;
  const int t = threadIdx.x;
  const int base = t * 49;
  int s = 0;
  for (int j = 0; j < 49; ++j) {
    int idx = base + j;
    if (idx < NN) s += cnt[idx];
  }
  sums[t] = s;
  __syncthreads();
  for (int off = 1; off < 1024; off <<= 1) {
    int add = (t >= off) ? sums[t - off] : 0;
    __syncthreads();
    sums[t] += add;
    __syncthreads();
  }
  int run = (t == 0) ? 0 : sums[t - 1];
  for (int j = 0; j < 49; ++j) {
    int idx = base + j;
    if (idx < NN) {
      offs[idx] = run; cur[idx] = run;
      run += cnt[idx];
    }
  }
}

__global__ __launch_bounds__(256) void fill_both_kernel(
    const int* __restrict__ rowIdx, const int* __restrict__ colIdx,
    const int* __restrict__ batch,
    int* __restrict__ cur_r, int* __restrict__ cur_s,
    int* __restrict__ posr, int* __restrict__ eidlist_r,
    int* __restrict__ eidlist_s, int* __restrict__ gs,
    int* __restrict__ segidx) {
  int i = blockIdx.x * 256 + threadIdx.x;
  if (i < NE) {
    const int c = colIdx[i];
    const int p = atomicAdd(&cur_r[c], 1);
    posr[i] = p;
    eidlist_r[p] = i;
    const int r = rowIdx[i];
    const int p2 = atomicAdd(&cur_s[r], 1);
    eidlist_s[p2] = i;
    gs[p2] = batch[r];
    segidx[p2] = p;
  }
}

// ---------------- edge MLP (round-19 + nontemporal e2b stores) --------
__global__ __launch_bounds__(256, 3) void edge_kernel(
    const float* __restrict__ ef,
    const unsigned short* __restrict__ PQ,
    const float* __restrict__ Rg,
    const int* __restrict__ rowI, const int* __restrict__ colI,
    const int* __restrict__ batch, const int* __restrict__ posr,
    const unsigned short* __restrict__ W1eT,
    const unsigned short* __restrict__ W2T,
    const float* __restrict__ b1, const float* __restrict__ b2,
    const float* __restrict__ gam, const float* __restrict__ bet,
    float* __restrict__ outE, unsigned short* __restrict__ e2b) {
  __shared__ __align__(16) char U[27648];
  __shared__ __align__(16) unsigned short Hsm[64][136];
  __shared__ float cb1[128], cb2[128], cg[128], cbt[128];
  unsigned short (*B1e)[40] = (unsigned short(*)[40])U;
  unsigned short (*Ssm)[136] = (unsigned short(*)[136])(U + 10240);
  unsigned short (*Bsm)[72] = (unsigned short(*)[72])U;

  const int tid = threadIdx.x;
  const int base = blockIdx.x * 64;
  if (tid < 128) {
    cb1[tid] = b1[tid]; cb2[tid] = b2[tid];
    cg[tid] = gam[tid]; cbt[tid] = bet[tid];
    const uint4* s = (const uint4*)(W1eT + tid * 32);
#pragma unroll
    for (int k = 0; k < 4; ++k) *(uint4*)&B1e[tid][k * 8] = s[k];
  }

  {
    const int r = tid >> 2, q = tid & 3;
    const int grow = base + r;
    const int rcv = colI[grow];
    const int snd = rowI[grow];
    const int g = batch[snd];
    const uint4* pp = (const uint4*)(PQ + (size_t)rcv * 256 + q * 32);
    const uint4* qq = (const uint4*)(PQ + (size_t)snd * 256 + 128 + q * 32);
    const float4* rr = (const float4*)(Rg + g * 128 + q * 32);
#pragma unroll
    for (int k = 0; k < 4; ++k) {
      uint4 pv = pp[k], qv = qq[k];
      float4 r0 = rr[2 * k], r1 = rr[2 * k + 1];
      unsigned o0 = (unsigned)f2bf(bflo(pv.x) + bflo(qv.x) + r0.x)
                  | ((unsigned)f2bf(bfhi(pv.x) + bfhi(qv.x) + r0.y) << 16);
      unsigned o1 = (unsigned)f2bf(bflo(pv.y) + bflo(qv.y) + r0.z)
                  | ((unsigned)f2bf(bfhi(pv.y) + bfhi(qv.y) + r0.w) << 16);
      unsigned o2 = (unsigned)f2bf(bflo(pv.z) + bflo(qv.z) + r1.x)
                  | ((unsigned)f2bf(bfhi(pv.z) + bfhi(qv.z) + r1.y) << 16);
      unsigned o3 = (unsigned)f2bf(bflo(pv.w) + bflo(qv.w) + r1.z)
                  | ((unsigned)f2bf(bfhi(pv.w) + bfhi(qv.w) + r1.w) << 16);
      *(uint4*)&Ssm[r][q * 32 + k * 8] = uint4{o0, o1, o2, o3};
    }
  }
  __syncthreads();

  const int w = tid >> 6, lane = tid & 63;
  const int l15 = lane & 15, lg = lane >> 4;

  f32x4 acc[8];
#pragma unroll
  for (int ni = 0; ni < 8; ++ni) acc[ni] = f32x4{0.f, 0.f, 0.f, 0.f};
  {
    const int arow = base + w * 16 + l15;
    const float* ep = ef + (size_t)arow * 32 + lg * 8;
    float4 v0 = *(const float4*)ep;
    float4 v1 = *(const float4*)(ep + 4);
    bf16x8 a;
    a[0] = (short)f2bf(v0.x); a[1] = (short)f2bf(v0.y);
    a[2] = (short)f2bf(v0.z); a[3] = (short)f2bf(v0.w);
    a[4] = (short)f2bf(v1.x); a[5] = (short)f2bf(v1.y);
    a[6] = (short)f2bf(v1.z); a[7] = (short)f2bf(v1.w);
#pragma unroll
    for (int ni = 0; ni < 8; ++ni) {
      bf16x8 b0 = *(bf16x8*)&B1e[ni * 16 + l15][lg * 8];
      acc[ni] = MFMA16(a, b0, acc[ni]);
    }
  }

#pragma unroll
  for (int ni = 0; ni < 8; ++ni) {
    const int ncol = l15 + ni * 16;
    const float bias = cb1[ncol];
#pragma unroll
    for (int reg = 0; reg < 4; ++reg) {
      const int mrow = w * 16 + lg * 4 + reg;
      const float sv = bf2f(Ssm[mrow][ncol]);
      Hsm[mrow][ncol] = f2bf(fmaxf(acc[ni][reg] + sv + bias, 0.f));
    }
  }
  __syncthreads();

  f32x4 acc2[8];
#pragma unroll
  for (int ni = 0; ni < 8; ++ni) acc2[ni] = f32x4{0.f, 0.f, 0.f, 0.f};
  for (int kc = 0; kc < 2; ++kc) {
    {
      const int n = tid >> 1, half = tid & 1;
      const uint4* src = (const uint4*)(W2T + (size_t)n * 128 + kc * 64 + half * 32);
#pragma unroll
      for (int k = 0; k < 4; ++k)
        *(uint4*)&Bsm[n][half * 32 + k * 8] = src[k];
    }
    __syncthreads();
    bf16x8 a0 = *(bf16x8*)&Hsm[w * 16 + l15][kc * 64 + lg * 8];
    bf16x8 a1 = *(bf16x8*)&Hsm[w * 16 + l15][kc * 64 + 32 + lg * 8];
#pragma unroll
    for (int ni = 0; ni < 8; ++ni) {
      bf16x8 b0 = *(bf16x8*)&Bsm[ni * 16 + l15][lg * 8];
      bf16x8 b1 = *(bf16x8*)&Bsm[ni * 16 + l15][32 + lg * 8];
      acc2[ni] = MFMA16(a0, b0, acc2[ni]);
      acc2[ni] = MFMA16(a1, b1, acc2[ni]);
    }
    __syncthreads();
  }

  float hv[8][4];
  float sreg[4] = {0.f, 0.f, 0.f, 0.f}, ssreg[4] = {0.f, 0.f, 0.f, 0.f};
#pragma unroll
  for (int ni = 0; ni < 8; ++ni) {
    const int ncol = l15 + ni * 16;
    const float bias = cb2[ncol];
#pragma unroll
    for (int reg = 0; reg < 4; ++reg) {
      const float h = fmaxf(acc2[ni][reg] + bias, 0.f);
      hv[ni][reg] = h;
      sreg[reg] += h; ssreg[reg] += h * h;
    }
  }
#pragma unroll
  for (int reg = 0; reg < 4; ++reg) {
    float s = sreg[reg], ss = ssreg[reg];
#pragma unroll
    for (int off = 1; off < 16; off <<= 1) {
      s += __shfl_xor(s, off, 64);
      ss += __shfl_xor(ss, off, 64);
    }
    sreg[reg] = s; ssreg[reg] = ss;
  }
#pragma unroll
  for (int reg = 0; reg < 4; ++reg) {
    const int mrow = w * 16 + lg * 4 + reg;
    const int grow = base + mrow;
    const float mu = sreg[reg] * (1.f / 128.f);
    const float var = ssreg[reg] * (1.f / 128.f) - mu * mu;
    const float rstd = rsqrtf(var + EPSV);
#pragma unroll
    for (int ni = 0; ni < 8; ++ni) {
      const int ncol = l15 + ni * 16;
      const float y = cg[ncol] * (hv[ni][reg] - mu) * rstd + cbt[ncol];
      __builtin_nontemporal_store(y, &outE[(size_t)grow * 128 + ncol]);
      if (e2b) Hsm[mrow][ncol] = f2bf(y);
    }
  }
  if (e2b) {
    __syncthreads();
    const int r = tid >> 2, q = tid & 3;
    const int drow = posr[base + r];
#pragma unroll
    for (int k = 0; k < 4; ++k) {
      u32x4 v = *(u32x4*)&Hsm[r][q * 32 + k * 8];
      __builtin_nontemporal_store(
          v, (u32x4*)(e2b + (size_t)drow * 128 + q * 32 + k * 8));
    }
  }
}

// ---------------- fused post kernel: seg (0..SEGB-1) + node (rest) ----------
template <int BF>
__global__ __launch_bounds__(256, 2) void post_kernel(
    const float* __restrict__ outE, const unsigned short* __restrict__ e2b,
    const int* __restrict__ segA, const int* __restrict__ gsA,
    float* __restrict__ e2g,
    const unsigned short* __restrict__ xb,
    const unsigned short* __restrict__ ub,
    const int* __restrict__ batch,
    const int* __restrict__ offs, const int* __restrict__ cnt,
    const int* __restrict__ eidlist,
    const unsigned short* __restrict__ W1T,
    const unsigned short* __restrict__ W2T,
    const float* __restrict__ b1, const float* __restrict__ b2,
    const float* __restrict__ gam, const float* __restrict__ bet,
    float* __restrict__ outX, float* __restrict__ n2g) {
  __shared__ __align__(16) char U[50176];
  __shared__ __align__(16) unsigned short Bsm[128][72];
  __shared__ float cb1[128], cb2[128], cg[128], cbt[128];

  const int tid = threadIdx.x;

  if (blockIdx.x < SEGB) {
    const int c4 = (tid & 31) * 4;
    const int sub = tid >> 5;
    const int start = blockIdx.x * 800;
    int gcur = gsA[start + sub];
    float4 acc = {0.f, 0.f, 0.f, 0.f};
    for (int it = 0; it < 25; ++it) {
      const int pbase = start + sub + it * 32;
      int eid[4], g[4];
#pragma unroll
      for (int j = 0; j < 4; ++j) {
        eid[j] = segA[pbase + j * 8];
        g[j]   = gsA[pbase + j * 8];
      }
      float4 v[4];
      if (BF) {
#pragma unroll
        for (int j = 0; j < 4; ++j) {
          ushort4 h = *(const ushort4*)(e2b + (size_t)eid[j] * 128 + c4);
          v[j] = float4{bf2f(h.x), bf2f(h.y), bf2f(h.z), bf2f(h.w)};
        }
      } else {
#pragma unroll
        for (int j = 0; j < 4; ++j)
          v[j] = *(const float4*)(outE + (size_t)eid[j] * 128 + c4);
      }
#pragma unroll
      for (int j = 0; j < 4; ++j) {
        if (g[j] != gcur) {
          atomicAdd(&e2g[gcur * 128 + c4],     acc.x);
          atomicAdd(&e2g[gcur * 128 + c4 + 1], acc.y);
          atomicAdd(&e2g[gcur * 128 + c4 + 2], acc.z);
          atomicAdd(&e2g[gcur * 128 + c4 + 3], acc.w);
          gcur = g[j]; acc = float4{0.f, 0.f, 0.f, 0.f};
        }
        acc.x += v[j].x; acc.y += v[j].y; acc.z += v[j].z; acc.w += v[j].w;
      }
    }
    atomicAdd(&e2g[gcur * 128 + c4],     acc.x);
    atomicAdd(&e2g[gcur * 128 + c4 + 1], acc.y);
    atomicAdd(&e2g[gcur * 128 + c4 + 2], acc.z);
    atomicAdd(&e2g[gcur * 128 + c4 + 3], acc.w);
    return;
  }

  const int bx = blockIdx.x - SEGB;
  unsigned short (*Asm)[328] = (unsigned short(*)[328])U;
  unsigned short (*Hsm)[136] = (unsigned short(*)[136])U;
  float* bins = (float*)(U + 17408);

  if (tid < 128) {
    cb1[tid] = b1[tid]; cb2[tid] = b2[tid];
    cg[tid] = gam[tid]; cbt[tid] = bet[tid];
  }

  {
    const int r = tid >> 2, q = tid & 3;
    const int grow = bx * 64 + r;
    const bool valid = grow < NN;
    const uint4 zero = {0u, 0u, 0u, 0u};
    if (valid) {
      const uint4* xs = (const uint4*)(xb + (size_t)grow * 128 + q * 32);
#pragma unroll
      for (int k = 0; k < 4; ++k) *(uint4*)&Asm[r][q * 32 + k * 8] = xs[k];
    } else {
#pragma unroll
      for (int k = 0; k < 4; ++k) *(uint4*)&Asm[r][q * 32 + k * 8] = zero;
    }
    float4 a[8];
#pragma unroll
    for (int k = 0; k < 8; ++k) a[k] = float4{0.f, 0.f, 0.f, 0.f};
    if (valid) {
      const int start = offs[grow];
      const int deg = cnt[grow];
      int j = 0;
      for (; j + 2 <= deg; j += 2) {
        if (BF) {
          const uint4* s0 = (const uint4*)(e2b + (size_t)(start + j) * 128 + q * 32);
          const uint4* s1 = (const uint4*)(e2b + (size_t)(start + j + 1) * 128 + q * 32);
#pragma unroll
          for (int k = 0; k < 4; ++k) {
            uint4 v0 = s0[k], v1 = s1[k];
            a[2 * k].x     += bflo(v0.x) + bflo(v1.x);
            a[2 * k].y     += bfhi(v0.x) + bfhi(v1.x);
            a[2 * k].z     += bflo(v0.y) + bflo(v1.y);
            a[2 * k].w     += bfhi(v0.y) + bfhi(v1.y);
            a[2 * k + 1].x += bflo(v0.z) + bflo(v1.z);
            a[2 * k + 1].y += bfhi(v0.z) + bfhi(v1.z);
            a[2 * k + 1].z += bflo(v0.w) + bflo(v1.w);
            a[2 * k + 1].w += bfhi(v0.w) + bfhi(v1.w);
          }
        } else {
          const int e0 = eidlist[start + j], e1 = eidlist[start + j + 1];
          const float4* s0 = (const float4*)(outE + (size_t)e0 * 128 + q * 32);
          const float4* s1 = (const float4*)(outE + (size_t)e1 * 128 + q * 32);
#pragma unroll
          for (int k = 0; k < 8; ++k) {
            float4 v0 = s0[k], v1 = s1[k];
            a[k].x += v0.x + v1.x; a[k].y += v0.y + v1.y;
            a[k].z += v0.z + v1.z; a[k].w += v0.w + v1.w;
          }
        }
      }
      if (j < deg) {
        if (BF) {
          const uint4* s0 = (const uint4*)(e2b + (size_t)(start + j) * 128 + q * 32);
#pragma unroll
          for (int k = 0; k < 4; ++k) {
            uint4 v0 = s0[k];
            a[2 * k].x     += bflo(v0.x);
            a[2 * k].y     += bfhi(v0.x);
            a[2 * k].z     += bflo(v0.y);
            a[2 * k].w     += bfhi(v0.y);
            a[2 * k + 1].x += bflo(v0.z);
            a[2 * k + 1].y += bfhi(v0.z);
            a[2 * k + 1].z += bflo(v0.w);
            a[2 * k + 1].w += bfhi(v0.w);
          }
        } else {
          const int e0 = eidlist[start + j];
          const float4* s0 = (const float4*)(outE + (size_t)e0 * 128 + q * 32);
#pragma unroll
          for (int k = 0; k < 8; ++k) {
            float4 v0 = s0[k];
            a[k].x += v0.x; a[k].y += v0.y; a[k].z += v0.z; a[k].w += v0.w;
          }
        }
      }
    }
#pragma unroll
    for (int k = 0; k < 8; ++k) {
      ushort4 o;
      o.x = f2bf(a[k].x); o.y = f2bf(a[k].y);
      o.z = f2bf(a[k].z); o.w = f2bf(a[k].w);
      *(ushort4*)&Asm[r][128 + q * 32 + k * 4] = o;
    }
    const int g = valid ? batch[grow] : 0;
    uint4 uv = valid ? *(const uint4*)(ub + g * 32 + q * 8) : zero;
    *(uint4*)&Asm[r][256 + q * 8] = uv;
    *(uint4*)&Asm[r][288 + q * 8] = zero;
  }

  const int w = tid >> 6;
  const int lane = tid & 63;
  const int l15 = lane & 15, lg = lane >> 4;

  f32x4 acc[8];
#pragma unroll
  for (int ni = 0; ni < 8; ++ni) acc[ni] = f32x4{0.f, 0.f, 0.f, 0.f};

  for (int kc = 0; kc < 5; ++kc) {
    {
      const int n = tid >> 1, half = tid & 1;
      const uint4* src = (const uint4*)(W1T + (size_t)n * 320 + kc * 64 + half * 32);
#pragma unroll
      for (int k = 0; k < 4; ++k)
        *(uint4*)&Bsm[n][half * 32 + k * 8] = src[k];
    }
    __syncthreads();
    bf16x8 a0 = *(bf16x8*)&Asm[w * 16 + l15][kc * 64 + lg * 8];
    bf16x8 a1 = *(bf16x8*)&Asm[w * 16 + l15][kc * 64 + 32 + lg * 8];
#pragma unroll
    for (int ni = 0; ni < 8; ++ni) {
      bf16x8 bb0 = *(bf16x8*)&Bsm[ni * 16 + l15][lg * 8];
      bf16x8 bb1 = *(bf16x8*)&Bsm[ni * 16 + l15][32 + lg * 8];
      acc[ni] = MFMA16(a0, bb0, acc[ni]);
      acc[ni] = MFMA16(a1, bb1, acc[ni]);
    }
    __syncthreads();
  }

#pragma unroll
  for (int ni = 0; ni < 8; ++ni) {
    const int ncol = l15 + ni * 16;
    const float bias = cb1[ncol];
#pragma unroll
    for (int reg = 0; reg < 4; ++reg) {
      const int mrow = w * 16 + lg * 4 + reg;
      Hsm[mrow][ncol] = f2bf(fmaxf(acc[ni][reg] + bias, 0.f));
    }
  }
  for (int i = tid; i < NG * 128; i += 256) bins[i] = 0.f;

  f32x4 acc2[8];
#pragma unroll
  for (int ni = 0; ni < 8; ++ni) acc2[ni] = f32x4{0.f, 0.f, 0.f, 0.f};
  for (int kc = 0; kc < 2; ++kc) {
    {
      const int n = tid >> 1, half = tid & 1;
      const uint4* src = (const uint4*)(W2T + (size_t)n * 128 + kc * 64 + half * 32);
#pragma unroll
      for (int k = 0; k < 4; ++k)
        *(uint4*)&Bsm[n][half * 32 + k * 8] = src[k];
    }
    __syncthreads();
    bf16x8 a0 = *(bf16x8*)&Hsm[w * 16 + l15][kc * 64 + lg * 8];
    bf16x8 a1 = *(bf16x8*)&Hsm[w * 16 + l15][kc * 64 + 32 + lg * 8];
#pragma unroll
    for (int ni = 0; ni < 8; ++ni) {
      bf16x8 bb0 = *(bf16x8*)&Bsm[ni * 16 + l15][lg * 8];
      bf16x8 bb1 = *(bf16x8*)&Bsm[ni * 16 + l15][32 + lg * 8];
      acc2[ni] = MFMA16(a0, bb0, acc2[ni]);
      acc2[ni] = MFMA16(a1, bb1, acc2[ni]);
    }
    __syncthreads();
  }

  float hv[8][4];
  float sreg[4] = {0.f, 0.f, 0.f, 0.f}, ssreg[4] = {0.f, 0.f, 0.f, 0.f};
#pragma unroll
  for (int ni = 0; ni < 8; ++ni) {
    const int ncol = l15 + ni * 16;
    const float bias = cb2[ncol];
#pragma unroll
    for (int reg = 0; reg < 4; ++reg) {
      const float h = fmaxf(acc2[ni][reg] + bias, 0.f);
      hv[ni][reg] = h;
      sreg[reg] += h; ssreg[reg] += h * h;
    }
  }
#pragma unroll
  for (int reg = 0; reg < 4; ++reg) {
    float s = sreg[reg], ss = ssreg[reg];
#pragma unroll
    for (int off = 1; off < 16; off <<= 1) {
      s += __shfl_xor(s, off, 64);
      ss += __shfl_xor(ss, off, 64);
    }
    sreg[reg] = s; ssreg[reg] = ss;
  }
#pragma unroll
  for (int reg = 0; reg < 4; ++reg) {
    const int mrow = w * 16 + lg * 4 + reg;
    const int grow = bx * 64 + mrow;
    if (grow >= NN) continue;
    const float mu = sreg[reg] * (1.f / 128.f);
    const float var = ssreg[reg] * (1.f / 128.f) - mu * mu;
    const float rstd = rsqrtf(var + EPSV);
    const int g = batch[grow];
#pragma unroll
    for (int ni = 0; ni < 8; ++ni) {
      const int ncol = l15 + ni * 16;
      const float y = cg[ncol] * (hv[ni][reg] - mu) * rstd + cbt[ncol];
      __builtin_nontemporal_store(y, &outX[(size_t)grow * 128 + ncol]);
      atomicAdd(&bins[g * 128 + ncol], y);
    }
  }
  __syncthreads();
  const int first = bx * 64;
  const int last = min(first + 63, NN - 1);
  const int gmin = batch[first], gmax = batch[last];
  const int cntf = (gmax - gmin + 1) * 128;
  for (int i = tid; i < cntf; i += 256)
    atomicAdd(&n2g[gmin * 128 + i], bins[gmin * 128 + i]);
}

// ---------------- global MLP (tiny) ----------------
__global__ __launch_bounds__(128) void glob_kernel(
    const float* __restrict__ u, const float* __restrict__ n2g,
    const float* __restrict__ e2g,
    const float* __restrict__ gW1, const float* __restrict__ gb1,
    const float* __restrict__ gW2, const float* __restrict__ gb2,
    const float* __restrict__ gg, const float* __restrict__ gbt,
    float* __restrict__ outU) {
  __shared__ float in[288];
  __shared__ float h1[128];
  __shared__ float red[4];
  const int g = blockIdx.x, t = threadIdx.x;
  if (t < 32) in[t] = u[g * 32 + t];
  in[32 + t] = n2g[g * 128 + t];
  in[160 + t] = e2g[g * 128 + t];
  __syncthreads();
  float a = gb1[t];
  for (int k = 0; k < 288; ++k) a += in[k] * gW1[k * 128 + t];
  h1[t] = fmaxf(a, 0.f);
  __syncthreads();
  float h = gb2[t];
  for (int k = 0; k < 128; ++k) h += h1[k] * gW2[k * 128 + t];
  h = fmaxf(h, 0.f);
  float s = h, ss = h * h;
  for (int off = 1; off < 64; off <<= 1) {
    s += __shfl_xor(s, off, 64);
    ss += __shfl_xor(ss, off, 64);
  }
  if ((t & 63) == 0) { red[(t >> 6) * 2] = s; red[(t >> 6) * 2 + 1] = ss; }
  __syncthreads();
  const float S = red[0] + red[2], SS = red[1] + red[3];
  const float mu = S * (1.f / 128.f);
  const float var = SS * (1.f / 128.f) - mu * mu;
  const float rstd = rsqrtf(var + EPSV);
  outU[g * 128 + t] = gg[t] * (h - mu) * rstd + gbt[t];
}

// ---------------- launch ----------------
extern "C" void kernel_launch(void* const* d_in, const int* in_sizes, int n_in,
                              void* d_out, int out_size, void* d_ws,
                              size_t ws_size, hipStream_t stream) {
  const float* x   = (const float*)d_in[0];
  const float* e   = (const float*)d_in[1];
  const float* u   = (const float*)d_in[2];
  const int* eidx  = (const int*)d_in[3];
  const int* batch = (const int*)d_in[4];
  const float* eW1 = (const float*)d_in[5];
  const float* eb1 = (const float*)d_in[6];
  const float* eW2 = (const float*)d_in[7];
  const float* eb2 = (const float*)d_in[8];
  const float* eg  = (const float*)d_in[9];
  const float* ebt = (const float*)d_in[10];
  const float* nW1 = (const float*)d_in[11];
  const float* nb1 = (const float*)d_in[12];
  const float* nW2 = (const float*)d_in[13];
  const float* nb2 = (const float*)d_in[14];
  const float* ng  = (const float*)d_in[15];
  const float* nbt = (const float*)d_in[16];
  const float* gW1 = (const float*)d_in[17];
  const float* gb1 = (const float*)d_in[18];
  const float* gW2 = (const float*)d_in[19];
  const float* gb2 = (const float*)d_in[20];
  const float* gg  = (const float*)d_in[21];
  const float* gbt = (const float*)d_in[22];

  char* ws = (char*)d_ws;
  float* e2g           = (float*)(ws + 0);
  float* n2g           = (float*)(ws + 32768);
  int*   cnt_r         = (int*)  (ws + 65536);
  int*   cnt_s         = (int*)  (ws + 265536);
  int*   offs_r        = (int*)  (ws + 465536);
  int*   cur_r         = (int*)  (ws + 665536);
  int*   offs_s        = (int*)  (ws + 865536);
  int*   cur_s         = (int*)  (ws + 1065536);
  int*   eidlist_r     = (int*)  (ws + 1265536);
  int*   eidlist_s     = (int*)  (ws + 4465536);
  int*   gs            = (int*)  (ws + 7665536);
  int*   posr          = (int*)  (ws + 10865536);
  int*   segidx        = (int*)  (ws + 14065536);
  unsigned short* xb   = (unsigned short*)(ws + 17265536);
  unsigned short* ub   = (unsigned short*)(ws + 30065536);
  unsigned short* W1eT = (unsigned short*)(ws + 30069632);
  unsigned short* WpqT = (unsigned short*)(ws + 30077824);
  unsigned short* eW2T = (unsigned short*)(ws + 30143360);
  unsigned short* nW1T = (unsigned short*)(ws + 30176128);
  unsigned short* nW2T = (unsigned short*)(ws + 30258048);
  unsigned short* PQ   = (unsigned short*)(ws + 30290816);
  float* Rg            = (float*)(ws + 55890816);
  unsigned short* e2b  = (unsigned short*)(ws + 55923584);  // 204,800,000 B
  const bool useB = ws_size >= (size_t)55923584 + 204800000;

  hipMemsetAsync(ws, 0, 465536, stream);

  const int* rowI = eidx;
  const int* colI = eidx + NE;

  cvt_pre_kernel<<<1024, 256, 0, stream>>>(x, xb, rowI, colI, cnt_r, cnt_s);
  cvt_small_kernel<<<472, 256, 0, stream>>>(u, eW1, eW2, nW1, nW2, ub, W1eT,
                                            WpqT, eW2T, nW1T, nW2T, Rg);
  pq_kernel<<<(NN + 63) / 64, 256, 0, stream>>>(xb, WpqT, PQ);

  float* outX = (float*)d_out;
  float* outE = outX + (size_t)NN * 128;
  float* outU = outE + (size_t)NE * 128;

  scan2_kernel<<<2, 1024, 0, stream>>>(cnt_r, offs_r, cur_r,
                                       cnt_s, offs_s, cur_s);
  fill_both_kernel<<<(NE + 255) / 256, 256, 0, stream>>>(
      rowI, colI, batch, cur_r, cur_s, posr, eidlist_r, eidlist_s, gs, segidx);

  edge_kernel<<<NE / 64, 256, 0, stream>>>(e, PQ, Rg, rowI, colI, batch, posr,
                                           W1eT, eW2T, eb1, eb2, eg, ebt,
                                           outE, useB ? e2b : nullptr);
  if (useB) {
    post_kernel<1><<<SEGB + (NN + 63) / 64, 256, 0, stream>>>(
        outE, e2b, segidx, gs, e2g,
        xb, ub, batch, offs_r, cnt_r, eidlist_r,
        nW1T, nW2T, nb1, nb2, ng, nbt, outX, n2g);
  } else {
    post_kernel<0><<<SEGB + (NN + 63) / 64, 256, 0, stream>>>(
        outE, e2b, eidlist_s, gs, e2g,
        xb, ub, batch, offs_r, cnt_r, eidlist_r,
        nW1T, nW2T, nb1, nb2, ng, nbt, outX, n2g);
  }
  glob_kernel<<<NG, 128, 0, stream>>>(u, n2g, e2g, gW1, gb1, gW2, gb2, gg, gbt,
                                      outU);
}

// Round 24
// 762.260 us; speedup vs baseline: 1.1990x; 1.1990x over previous
//
#include <hip/hip_runtime.h>
#include <hip/hip_bf16.h>

typedef __attribute__((ext_vector_type(8))) short bf16x8;
typedef __attribute__((ext_vector_type(4))) float f32x4;

#define EPSV 1e-5f
#define NN 50000
#define NE 800000
#define NG 64
#define SEGB 1000
#define MFMA16(a, b, c) __builtin_amdgcn_mfma_f32_16x16x32_bf16(a, b, c, 0, 0, 0)

__device__ __forceinline__ unsigned short f2bf(float f) {
  __hip_bfloat16 h = __float2bfloat16(f);   // HW RNE convert on gfx950
  union { __hip_bfloat16 b; unsigned short u; } v; v.b = h;
  return v.u;
}
__device__ __forceinline__ float bf2f(unsigned short h) {
  union { unsigned u; float f; } v; v.u = ((unsigned)h) << 16;
  return v.f;
}
__device__ __forceinline__ float bflo(unsigned u) {
  union { unsigned x; float f; } v; v.x = u << 16; return v.f;
}
__device__ __forceinline__ float bfhi(unsigned u) {
  union { unsigned x; float f; } v; v.x = u & 0xffff0000u; return v.f;
}

// ---------------- conversion + edge-histogram (fused) ----------------

__global__ __launch_bounds__(256) void cvt_pre_kernel(
    const float* __restrict__ x, unsigned short* __restrict__ xb,
    const int* __restrict__ rowIdx, const int* __restrict__ colIdx,
    int* __restrict__ cnt_r, int* __restrict__ cnt_s) {
  const int NX4 = (NN * 128) / 4;   // 1,600,000 >= NE
  for (int idx = blockIdx.x * 256 + threadIdx.x; idx < NX4;
       idx += gridDim.x * 256) {
    float4 v = ((const float4*)x)[idx];
    ushort4 o;
    o.x = f2bf(v.x); o.y = f2bf(v.y); o.z = f2bf(v.z); o.w = f2bf(v.w);
    ((ushort4*)xb)[idx] = o;
    if (idx < NE) {
      atomicAdd(&cnt_r[colIdx[idx]], 1);
      atomicAdd(&cnt_s[rowIdx[idx]], 1);
    }
  }
}

__global__ __launch_bounds__(256) void cvt_small_kernel(
    const float* __restrict__ u,
    const float* __restrict__ eW1, const float* __restrict__ eW2,
    const float* __restrict__ nW1, const float* __restrict__ nW2,
    unsigned short* __restrict__ ub,
    unsigned short* __restrict__ W1eT, unsigned short* __restrict__ WpqT,
    unsigned short* __restrict__ eW2T,
    unsigned short* __restrict__ nW1T, unsigned short* __restrict__ nW2T,
    float* __restrict__ Rg) {
  int i = blockIdx.x * 256 + threadIdx.x;
  const int R0 = NG * 32;
  const int R1 = R0 + 128 * 32;
  const int R2 = R1 + 256 * 128;
  const int R3 = R2 + 128 * 128;
  const int R4 = R3 + 128 * 320;
  const int R5 = R4 + 128 * 128;
  const int R6 = R5 + NG * 128;
  if (i < R0) {
    ub[i] = f2bf(u[i]);
  } else if (i < R1) {
    int j = i - R0; int n = j >> 5, k = j & 31;
    W1eT[j] = f2bf(eW1[k * 128 + n]);
  } else if (i < R2) {
    int j = i - R1; int n = j >> 7, k = j & 127;
    WpqT[j] = (n < 128) ? f2bf(eW1[(32 + k) * 128 + n])
                        : f2bf(eW1[(160 + k) * 128 + (n - 128)]);
  } else if (i < R3) {
    int j = i - R2; int n = j >> 7, k = j & 127;
    eW2T[j] = f2bf(eW2[k * 128 + n]);
  } else if (i < R4) {
    int j = i - R3; int n = j / 320, k = j % 320;
    nW1T[j] = (k < 288) ? f2bf(nW1[k * 128 + n]) : (unsigned short)0;
  } else if (i < R5) {
    int j = i - R4; int n = j >> 7, k = j & 127;
    nW2T[j] = f2bf(nW2[k * 128 + n]);
  } else if (i < R6) {
    int j = i - R5; int g = j >> 7, n = j & 127;
    float s = 0.f;
#pragma unroll
    for (int k = 0; k < 32; ++k) s += u[g * 32 + k] * eW1[(288 + k) * 128 + n];
    Rg[j] = s;
  }
}

// ---------------- PQ precompute ----------------
__global__ __launch_bounds__(256, 2) void pq_kernel(
    const unsigned short* __restrict__ xb,
    const unsigned short* __restrict__ WpqT,
    unsigned short* __restrict__ PQ) {
  __shared__ __align__(16) unsigned short Asm[64][136];
  __shared__ __align__(16) unsigned short Bsm[256][72];
  const int tid = threadIdx.x;
  {
    const int r = tid >> 2, q = tid & 3;
    const int grow = blockIdx.x * 64 + r;
    const uint4 zero = {0u, 0u, 0u, 0u};
    if (grow < NN) {
      const uint4* xs = (const uint4*)(xb + (size_t)grow * 128 + q * 32);
#pragma unroll
      for (int k = 0; k < 4; ++k) *(uint4*)&Asm[r][q * 32 + k * 8] = xs[k];
    } else {
#pragma unroll
      for (int k = 0; k < 4; ++k) *(uint4*)&Asm[r][q * 32 + k * 8] = zero;
    }
  }
  const int w = tid >> 6, lane = tid & 63;
  const int l15 = lane & 15, lg = lane >> 4;
  f32x4 acc[16];
#pragma unroll
  for (int ni = 0; ni < 16; ++ni) acc[ni] = f32x4{0.f, 0.f, 0.f, 0.f};
  for (int kc = 0; kc < 2; ++kc) {
    {
      const uint4* src = (const uint4*)(WpqT + (size_t)tid * 128 + kc * 64);
#pragma unroll
      for (int k = 0; k < 8; ++k) *(uint4*)&Bsm[tid][k * 8] = src[k];
    }
    __syncthreads();
    bf16x8 a0 = *(bf16x8*)&Asm[w * 16 + l15][kc * 64 + lg * 8];
    bf16x8 a1 = *(bf16x8*)&Asm[w * 16 + l15][kc * 64 + 32 + lg * 8];
#pragma unroll
    for (int ni = 0; ni < 16; ++ni) {
      bf16x8 b0 = *(bf16x8*)&Bsm[ni * 16 + l15][lg * 8];
      bf16x8 b1 = *(bf16x8*)&Bsm[ni * 16 + l15][32 + lg * 8];
      acc[ni] = MFMA16(a0, b0, acc[ni]);
      acc[ni] = MFMA16(a1, b1, acc[ni]);
    }
    __syncthreads();
  }
  unsigned short (*Cl)[264] = (unsigned short(*)[264])&Bsm[0][0];
#pragma unroll
  for (int ni = 0; ni < 16; ++ni)
#pragma unroll
    for (int reg = 0; reg < 4; ++reg)
      Cl[w * 16 + lg * 4 + reg][l15 + ni * 16] = f2bf(acc[ni][reg]);
  __syncthreads();
  {
    const int r = tid >> 2, q = tid & 3;
    const int grow = blockIdx.x * 64 + r;
    if (grow < NN) {
#pragma unroll
      for (int k = 0; k < 8; ++k)
        *(uint4*)(PQ + (size_t)grow * 256 + q * 64 + k * 8) =
            *(uint4*)&Cl[r][q * 64 + k * 8];
    }
  }
}

// ---------------- CSR construction ----------------

__global__ __launch_bounds__(1024) void scan2_kernel(
    const int* __restrict__ cnt_r, int* __restrict__ offs_r, int* __restrict__ cur_r,
    const int* __restrict__ cnt_s, int* __restrict__ offs_s, int* __restrict__ cur_s) {
  __shared__ int sums[1024];
  const int* cnt = blockIdx.x ? cnt_s : cnt_r;
  int* offs = blockIdx.x ? offs_s : offs_r;
  int* cur  = blockIdx.x ? cur_s : cur_r;
  const int t = threadIdx.x;
  const int base = t * 49;
  int s = 0;
  for (int j = 0; j < 49; ++j) {
    int idx = base + j;
    if (idx < NN) s += cnt[idx];
  }
  sums[t] = s;
  __syncthreads();
  for (int off = 1; off < 1024; off <<= 1) {
    int add = (t >= off) ? sums[t - off] : 0;
    __syncthreads();
    sums[t] += add;
    __syncthreads();
  }
  int run = (t == 0) ? 0 : sums[t - 1];
  for (int j = 0; j < 49; ++j) {
    int idx = base + j;
    if (idx < NN) {
      offs[idx] = run; cur[idx] = run;
      run += cnt[idx];
    }
  }
}

__global__ __launch_bounds__(256) void fill_both_kernel(
    const int* __restrict__ rowIdx, const int* __restrict__ colIdx,
    const int* __restrict__ batch,
    int* __restrict__ cur_r, int* __restrict__ cur_s,
    int* __restrict__ posr, int* __restrict__ eidlist_r,
    int* __restrict__ eidlist_s, int* __restrict__ gs,
    int* __restrict__ segidx) {
  int i = blockIdx.x * 256 + threadIdx.x;
  if (i < NE) {
    const int c = colIdx[i];
    const int p = atomicAdd(&cur_r[c], 1);
    posr[i] = p;
    eidlist_r[p] = i;
    const int r = rowIdx[i];
    const int p2 = atomicAdd(&cur_s[r], 1);
    eidlist_s[p2] = i;
    gs[p2] = batch[r];
    segidx[p2] = p;
  }
}

// ---------------- edge MLP (round-19 known-good: NT outE, cached e2b) -----
__global__ __launch_bounds__(256, 3) void edge_kernel(
    const float* __restrict__ ef,
    const unsigned short* __restrict__ PQ,
    const float* __restrict__ Rg,
    const int* __restrict__ rowI, const int* __restrict__ colI,
    const int* __restrict__ batch, const int* __restrict__ posr,
    const unsigned short* __restrict__ W1eT,
    const unsigned short* __restrict__ W2T,
    const float* __restrict__ b1, const float* __restrict__ b2,
    const float* __restrict__ gam, const float* __restrict__ bet,
    float* __restrict__ outE, unsigned short* __restrict__ e2b) {
  __shared__ __align__(16) char U[27648];
  __shared__ __align__(16) unsigned short Hsm[64][136];
  __shared__ float cb1[128], cb2[128], cg[128], cbt[128];
  unsigned short (*B1e)[40] = (unsigned short(*)[40])U;
  unsigned short (*Ssm)[136] = (unsigned short(*)[136])(U + 10240);
  unsigned short (*Bsm)[72] = (unsigned short(*)[72])U;

  const int tid = threadIdx.x;
  const int base = blockIdx.x * 64;
  if (tid < 128) {
    cb1[tid] = b1[tid]; cb2[tid] = b2[tid];
    cg[tid] = gam[tid]; cbt[tid] = bet[tid];
    const uint4* s = (const uint4*)(W1eT + tid * 32);
#pragma unroll
    for (int k = 0; k < 4; ++k) *(uint4*)&B1e[tid][k * 8] = s[k];
  }

  {
    const int r = tid >> 2, q = tid & 3;
    const int grow = base + r;
    const int rcv = colI[grow];
    const int snd = rowI[grow];
    const int g = batch[snd];
    const uint4* pp = (const uint4*)(PQ + (size_t)rcv * 256 + q * 32);
    const uint4* qq = (const uint4*)(PQ + (size_t)snd * 256 + 128 + q * 32);
    const float4* rr = (const float4*)(Rg + g * 128 + q * 32);
#pragma unroll
    for (int k = 0; k < 4; ++k) {
      uint4 pv = pp[k], qv = qq[k];
      float4 r0 = rr[2 * k], r1 = rr[2 * k + 1];
      unsigned o0 = (unsigned)f2bf(bflo(pv.x) + bflo(qv.x) + r0.x)
                  | ((unsigned)f2bf(bfhi(pv.x) + bfhi(qv.x) + r0.y) << 16);
      unsigned o1 = (unsigned)f2bf(bflo(pv.y) + bflo(qv.y) + r0.z)
                  | ((unsigned)f2bf(bfhi(pv.y) + bfhi(qv.y) + r0.w) << 16);
      unsigned o2 = (unsigned)f2bf(bflo(pv.z) + bflo(qv.z) + r1.x)
                  | ((unsigned)f2bf(bfhi(pv.z) + bfhi(qv.z) + r1.y) << 16);
      unsigned o3 = (unsigned)f2bf(bflo(pv.w) + bflo(qv.w) + r1.z)
                  | ((unsigned)f2bf(bfhi(pv.w) + bfhi(qv.w) + r1.w) << 16);
      *(uint4*)&Ssm[r][q * 32 + k * 8] = uint4{o0, o1, o2, o3};
    }
  }
  __syncthreads();

  const int w = tid >> 6, lane = tid & 63;
  const int l15 = lane & 15, lg = lane >> 4;

  f32x4 acc[8];
#pragma unroll
  for (int ni = 0; ni < 8; ++ni) acc[ni] = f32x4{0.f, 0.f, 0.f, 0.f};
  {
    const int arow = base + w * 16 + l15;
    const float* ep = ef + (size_t)arow * 32 + lg * 8;
    float4 v0 = *(const float4*)ep;
    float4 v1 = *(const float4*)(ep + 4);
    bf16x8 a;
    a[0] = (short)f2bf(v0.x); a[1] = (short)f2bf(v0.y);
    a[2] = (short)f2bf(v0.z); a[3] = (short)f2bf(v0.w);
    a[4] = (short)f2bf(v1.x); a[5] = (short)f2bf(v1.y);
    a[6] = (short)f2bf(v1.z); a[7] = (short)f2bf(v1.w);
#pragma unroll
    for (int ni = 0; ni < 8; ++ni) {
      bf16x8 b0 = *(bf16x8*)&B1e[ni * 16 + l15][lg * 8];
      acc[ni] = MFMA16(a, b0, acc[ni]);
    }
  }

#pragma unroll
  for (int ni = 0; ni < 8; ++ni) {
    const int ncol = l15 + ni * 16;
    const float bias = cb1[ncol];
#pragma unroll
    for (int reg = 0; reg < 4; ++reg) {
      const int mrow = w * 16 + lg * 4 + reg;
      const float sv = bf2f(Ssm[mrow][ncol]);
      Hsm[mrow][ncol] = f2bf(fmaxf(acc[ni][reg] + sv + bias, 0.f));
    }
  }
  __syncthreads();

  f32x4 acc2[8];
#pragma unroll
  for (int ni = 0; ni < 8; ++ni) acc2[ni] = f32x4{0.f, 0.f, 0.f, 0.f};
  for (int kc = 0; kc < 2; ++kc) {
    {
      const int n = tid >> 1, half = tid & 1;
      const uint4* src = (const uint4*)(W2T + (size_t)n * 128 + kc * 64 + half * 32);
#pragma unroll
      for (int k = 0; k < 4; ++k)
        *(uint4*)&Bsm[n][half * 32 + k * 8] = src[k];
    }
    __syncthreads();
    bf16x8 a0 = *(bf16x8*)&Hsm[w * 16 + l15][kc * 64 + lg * 8];
    bf16x8 a1 = *(bf16x8*)&Hsm[w * 16 + l15][kc * 64 + 32 + lg * 8];
#pragma unroll
    for (int ni = 0; ni < 8; ++ni) {
      bf16x8 b0 = *(bf16x8*)&Bsm[ni * 16 + l15][lg * 8];
      bf16x8 b1 = *(bf16x8*)&Bsm[ni * 16 + l15][32 + lg * 8];
      acc2[ni] = MFMA16(a0, b0, acc2[ni]);
      acc2[ni] = MFMA16(a1, b1, acc2[ni]);
    }
    __syncthreads();
  }

  float hv[8][4];
  float sreg[4] = {0.f, 0.f, 0.f, 0.f}, ssreg[4] = {0.f, 0.f, 0.f, 0.f};
#pragma unroll
  for (int ni = 0; ni < 8; ++ni) {
    const int ncol = l15 + ni * 16;
    const float bias = cb2[ncol];
#pragma unroll
    for (int reg = 0; reg < 4; ++reg) {
      const float h = fmaxf(acc2[ni][reg] + bias, 0.f);
      hv[ni][reg] = h;
      sreg[reg] += h; ssreg[reg] += h * h;
    }
  }
#pragma unroll
  for (int reg = 0; reg < 4; ++reg) {
    float s = sreg[reg], ss = ssreg[reg];
#pragma unroll
    for (int off = 1; off < 16; off <<= 1) {
      s += __shfl_xor(s, off, 64);
      ss += __shfl_xor(ss, off, 64);
    }
    sreg[reg] = s; ssreg[reg] = ss;
  }
#pragma unroll
  for (int reg = 0; reg < 4; ++reg) {
    const int mrow = w * 16 + lg * 4 + reg;
    const int grow = base + mrow;
    const float mu = sreg[reg] * (1.f / 128.f);
    const float var = ssreg[reg] * (1.f / 128.f) - mu * mu;
    const float rstd = rsqrtf(var + EPSV);
#pragma unroll
    for (int ni = 0; ni < 8; ++ni) {
      const int ncol = l15 + ni * 16;
      const float y = cg[ncol] * (hv[ni][reg] - mu) * rstd + cbt[ncol];
      __builtin_nontemporal_store(y, &outE[(size_t)grow * 128 + ncol]);
      if (e2b) Hsm[mrow][ncol] = f2bf(y);
    }
  }
  if (e2b) {
    __syncthreads();
    const int r = tid >> 2, q = tid & 3;
    const int drow = posr[base + r];
#pragma unroll
    for (int k = 0; k < 4; ++k)
      *(uint4*)(e2b + (size_t)drow * 128 + q * 32 + k * 8) =
          *(uint4*)&Hsm[r][q * 32 + k * 8];
  }
}

// ---------------- fused post kernel: seg (0..SEGB-1) + node (rest) ----------
template <int BF>
__global__ __launch_bounds__(256, 2) void post_kernel(
    const float* __restrict__ outE, const unsigned short* __restrict__ e2b,
    const int* __restrict__ segA, const int* __restrict__ gsA,
    float* __restrict__ e2g,
    const unsigned short* __restrict__ xb,
    const unsigned short* __restrict__ ub,
    const int* __restrict__ batch,
    const int* __restrict__ offs, const int* __restrict__ cnt,
    const int* __restrict__ eidlist,
    const unsigned short* __restrict__ W1T,
    const unsigned short* __restrict__ W2T,
    const float* __restrict__ b1, const float* __restrict__ b2,
    const float* __restrict__ gam, const float* __restrict__ bet,
    float* __restrict__ outX, float* __restrict__ n2g) {
  __shared__ __align__(16) char U[50176];
  __shared__ __align__(16) unsigned short Bsm[128][72];
  __shared__ float cb1[128], cb2[128], cg[128], cbt[128];

  const int tid = threadIdx.x;

  if (blockIdx.x < SEGB) {
    const int c4 = (tid & 31) * 4;
    const int sub = tid >> 5;
    const int start = blockIdx.x * 800;
    int gcur = gsA[start + sub];
    float4 acc = {0.f, 0.f, 0.f, 0.f};
    for (int it = 0; it < 25; ++it) {
      const int pbase = start + sub + it * 32;
      int eid[4], g[4];
#pragma unroll
      for (int j = 0; j < 4; ++j) {
        eid[j] = segA[pbase + j * 8];
        g[j]   = gsA[pbase + j * 8];
      }
      float4 v[4];
      if (BF) {
#pragma unroll
        for (int j = 0; j < 4; ++j) {
          ushort4 h = *(const ushort4*)(e2b + (size_t)eid[j] * 128 + c4);
          v[j] = float4{bf2f(h.x), bf2f(h.y), bf2f(h.z), bf2f(h.w)};
        }
      } else {
#pragma unroll
        for (int j = 0; j < 4; ++j)
          v[j] = *(const float4*)(outE + (size_t)eid[j] * 128 + c4);
      }
#pragma unroll
      for (int j = 0; j < 4; ++j) {
        if (g[j] != gcur) {
          atomicAdd(&e2g[gcur * 128 + c4],     acc.x);
          atomicAdd(&e2g[gcur * 128 + c4 + 1], acc.y);
          atomicAdd(&e2g[gcur * 128 + c4 + 2], acc.z);
          atomicAdd(&e2g[gcur * 128 + c4 + 3], acc.w);
          gcur = g[j]; acc = float4{0.f, 0.f, 0.f, 0.f};
        }
        acc.x += v[j].x; acc.y += v[j].y; acc.z += v[j].z; acc.w += v[j].w;
      }
    }
    atomicAdd(&e2g[gcur * 128 + c4],     acc.x);
    atomicAdd(&e2g[gcur * 128 + c4 + 1], acc.y);
    atomicAdd(&e2g[gcur * 128 + c4 + 2], acc.z);
    atomicAdd(&e2g[gcur * 128 + c4 + 3], acc.w);
    return;
  }

  const int bx = blockIdx.x - SEGB;
  unsigned short (*Asm)[328] = (unsigned short(*)[328])U;
  unsigned short (*Hsm)[136] = (unsigned short(*)[136])U;
  float* bins = (float*)(U + 17408);

  if (tid < 128) {
    cb1[tid] = b1[tid]; cb2[tid] = b2[tid];
    cg[tid] = gam[tid]; cbt[tid] = bet[tid];
  }

  {
    const int r = tid >> 2, q = tid & 3;
    const int grow = bx * 64 + r;
    const bool valid = grow < NN;
    const uint4 zero = {0u, 0u, 0u, 0u};
    if (valid) {
      const uint4* xs = (const uint4*)(xb + (size_t)grow * 128 + q * 32);
#pragma unroll
      for (int k = 0; k < 4; ++k) *(uint4*)&Asm[r][q * 32 + k * 8] = xs[k];
    } else {
#pragma unroll
      for (int k = 0; k < 4; ++k) *(uint4*)&Asm[r][q * 32 + k * 8] = zero;
    }
    float4 a[8];
#pragma unroll
    for (int k = 0; k < 8; ++k) a[k] = float4{0.f, 0.f, 0.f, 0.f};
    if (valid) {
      const int start = offs[grow];
      const int deg = cnt[grow];
      int j = 0;
      for (; j + 2 <= deg; j += 2) {
        if (BF) {
          const uint4* s0 = (const uint4*)(e2b + (size_t)(start + j) * 128 + q * 32);
          const uint4* s1 = (const uint4*)(e2b + (size_t)(start + j + 1) * 128 + q * 32);
#pragma unroll
          for (int k = 0; k < 4; ++k) {
            uint4 v0 = s0[k], v1 = s1[k];
            a[2 * k].x     += bflo(v0.x) + bflo(v1.x);
            a[2 * k].y     += bfhi(v0.x) + bfhi(v1.x);
            a[2 * k].z     += bflo(v0.y) + bflo(v1.y);
            a[2 * k].w     += bfhi(v0.y) + bfhi(v1.y);
            a[2 * k + 1].x += bflo(v0.z) + bflo(v1.z);
            a[2 * k + 1].y += bfhi(v0.z) + bfhi(v1.z);
            a[2 * k + 1].z += bflo(v0.w) + bflo(v1.w);
            a[2 * k + 1].w += bfhi(v0.w) + bfhi(v1.w);
          }
        } else {
          const int e0 = eidlist[start + j], e1 = eidlist[start + j + 1];
          const float4* s0 = (const float4*)(outE + (size_t)e0 * 128 + q * 32);
          const float4* s1 = (const float4*)(outE + (size_t)e1 * 128 + q * 32);
#pragma unroll
          for (int k = 0; k < 8; ++k) {
            float4 v0 = s0[k], v1 = s1[k];
            a[k].x += v0.x + v1.x; a[k].y += v0.y + v1.y;
            a[k].z += v0.z + v1.z; a[k].w += v0.w + v1.w;
          }
        }
      }
      if (j < deg) {
        if (BF) {
          const uint4* s0 = (const uint4*)(e2b + (size_t)(start + j) * 128 + q * 32);
#pragma unroll
          for (int k = 0; k < 4; ++k) {
            uint4 v0 = s0[k];
            a[2 * k].x     += bflo(v0.x);
            a[2 * k].y     += bfhi(v0.x);
            a[2 * k].z     += bflo(v0.y);
            a[2 * k].w     += bfhi(v0.y);
            a[2 * k + 1].x += bflo(v0.z);
            a[2 * k + 1].y += bfhi(v0.z);
            a[2 * k + 1].z += bflo(v0.w);
            a[2 * k + 1].w += bfhi(v0.w);
          }
        } else {
          const int e0 = eidlist[start + j];
          const float4* s0 = (const float4*)(outE + (size_t)e0 * 128 + q * 32);
#pragma unroll
          for (int k = 0; k < 8; ++k) {
            float4 v0 = s0[k];
            a[k].x += v0.x; a[k].y += v0.y; a[k].z += v0.z; a[k].w += v0.w;
          }
        }
      }
    }
#pragma unroll
    for (int k = 0; k < 8; ++k) {
      ushort4 o;
      o.x = f2bf(a[k].x); o.y = f2bf(a[k].y);
      o.z = f2bf(a[k].z); o.w = f2bf(a[k].w);
      *(ushort4*)&Asm[r][128 + q * 32 + k * 4] = o;
    }
    const int g = valid ? batch[grow] : 0;
    uint4 uv = valid ? *(const uint4*)(ub + g * 32 + q * 8) : zero;
    *(uint4*)&Asm[r][256 + q * 8] = uv;
    *(uint4*)&Asm[r][288 + q * 8] = zero;
  }

  const int w = tid >> 6;
  const int lane = tid & 63;
  const int l15 = lane & 15, lg = lane >> 4;

  f32x4 acc[8];
#pragma unroll
  for (int ni = 0; ni < 8; ++ni) acc[ni] = f32x4{0.f, 0.f, 0.f, 0.f};

  for (int kc = 0; kc < 5; ++kc) {
    {
      const int n = tid >> 1, half = tid & 1;
      const uint4* src = (const uint4*)(W1T + (size_t)n * 320 + kc * 64 + half * 32);
#pragma unroll
      for (int k = 0; k < 4; ++k)
        *(uint4*)&Bsm[n][half * 32 + k * 8] = src[k];
    }
    __syncthreads();
    bf16x8 a0 = *(bf16x8*)&Asm[w * 16 + l15][kc * 64 + lg * 8];
    bf16x8 a1 = *(bf16x8*)&Asm[w * 16 + l15][kc * 64 + 32 + lg * 8];
#pragma unroll
    for (int ni = 0; ni < 8; ++ni) {
      bf16x8 bb0 = *(bf16x8*)&Bsm[ni * 16 + l15][lg * 8];
      bf16x8 bb1 = *(bf16x8*)&Bsm[ni * 16 + l15][32 + lg * 8];
      acc[ni] = MFMA16(a0, bb0, acc[ni]);
      acc[ni] = MFMA16(a1, bb1, acc[ni]);
    }
    __syncthreads();
  }

#pragma unroll
  for (int ni = 0; ni < 8; ++ni) {
    const int ncol = l15 + ni * 16;
    const float bias = cb1[ncol];
#pragma unroll
    for (int reg = 0; reg < 4; ++reg) {
      const int mrow = w * 16 + lg * 4 + reg;
      Hsm[mrow][ncol] = f2bf(fmaxf(acc[ni][reg] + bias, 0.f));
    }
  }
  for (int i = tid; i < NG * 128; i += 256) bins[i] = 0.f;

  f32x4 acc2[8];
#pragma unroll
  for (int ni = 0; ni < 8; ++ni) acc2[ni] = f32x4{0.f, 0.f, 0.f, 0.f};
  for (int kc = 0; kc < 2; ++kc) {
    {
      const int n = tid >> 1, half = tid & 1;
      const uint4* src = (const uint4*)(W2T + (size_t)n * 128 + kc * 64 + half * 32);
#pragma unroll
      for (int k = 0; k < 4; ++k)
        *(uint4*)&Bsm[n][half * 32 + k * 8] = src[k];
    }
    __syncthreads();
    bf16x8 a0 = *(bf16x8*)&Hsm[w * 16 + l15][kc * 64 + lg * 8];
    bf16x8 a1 = *(bf16x8*)&Hsm[w * 16 + l15][kc * 64 + 32 + lg * 8];
#pragma unroll
    for (int ni = 0; ni < 8; ++ni) {
      bf16x8 bb0 = *(bf16x8*)&Bsm[ni * 16 + l15][lg * 8];
      bf16x8 bb1 = *(bf16x8*)&Bsm[ni * 16 + l15][32 + lg * 8];
      acc2[ni] = MFMA16(a0, bb0, acc2[ni]);
      acc2[ni] = MFMA16(a1, bb1, acc2[ni]);
    }
    __syncthreads();
  }

  float hv[8][4];
  float sreg[4] = {0.f, 0.f, 0.f, 0.f}, ssreg[4] = {0.f, 0.f, 0.f, 0.f};
#pragma unroll
  for (int ni = 0; ni < 8; ++ni) {
    const int ncol = l15 + ni * 16;
    const float bias = cb2[ncol];
#pragma unroll
    for (int reg = 0; reg < 4; ++reg) {
      const float h = fmaxf(acc2[ni][reg] + bias, 0.f);
      hv[ni][reg] = h;
      sreg[reg] += h; ssreg[reg] += h * h;
    }
  }
#pragma unroll
  for (int reg = 0; reg < 4; ++reg) {
    float s = sreg[reg], ss = ssreg[reg];
#pragma unroll
    for (int off = 1; off < 16; off <<= 1) {
      s += __shfl_xor(s, off, 64);
      ss += __shfl_xor(ss, off, 64);
    }
    sreg[reg] = s; ssreg[reg] = ss;
  }
#pragma unroll
  for (int reg = 0; reg < 4; ++reg) {
    const int mrow = w * 16 + lg * 4 + reg;
    const int grow = bx * 64 + mrow;
    if (grow >= NN) continue;
    const float mu = sreg[reg] * (1.f / 128.f);
    const float var = ssreg[reg] * (1.f / 128.f) - mu * mu;
    const float rstd = rsqrtf(var + EPSV);
    const int g = batch[grow];
#pragma unroll
    for (int ni = 0; ni < 8; ++ni) {
      const int ncol = l15 + ni * 16;
      const float y = cg[ncol] * (hv[ni][reg] - mu) * rstd + cbt[ncol];
      __builtin_nontemporal_store(y, &outX[(size_t)grow * 128 + ncol]);
      atomicAdd(&bins[g * 128 + ncol], y);
    }
  }
  __syncthreads();
  const int first = bx * 64;
  const int last = min(first + 63, NN - 1);
  const int gmin = batch[first], gmax = batch[last];
  const int cntf = (gmax - gmin + 1) * 128;
  for (int i = tid; i < cntf; i += 256)
    atomicAdd(&n2g[gmin * 128 + i], bins[gmin * 128 + i]);
}

// ---------------- global MLP (tiny) ----------------
__global__ __launch_bounds__(128) void glob_kernel(
    const float* __restrict__ u, const float* __restrict__ n2g,
    const float* __restrict__ e2g,
    const float* __restrict__ gW1, const float* __restrict__ gb1,
    const float* __restrict__ gW2, const float* __restrict__ gb2,
    const float* __restrict__ gg, const float* __restrict__ gbt,
    float* __restrict__ outU) {
  __shared__ float in[288];
  __shared__ float h1[128];
  __shared__ float red[4];
  const int g = blockIdx.x, t = threadIdx.x;
  if (t < 32) in[t] = u[g * 32 + t];
  in[32 + t] = n2g[g * 128 + t];
  in[160 + t] = e2g[g * 128 + t];
  __syncthreads();
  float a = gb1[t];
  for (int k = 0; k < 288; ++k) a += in[k] * gW1[k * 128 + t];
  h1[t] = fmaxf(a, 0.f);
  __syncthreads();
  float h = gb2[t];
  for (int k = 0; k < 128; ++k) h += h1[k] * gW2[k * 128 + t];
  h = fmaxf(h, 0.f);
  float s = h, ss = h * h;
  for (int off = 1; off < 64; off <<= 1) {
    s += __shfl_xor(s, off, 64);
    ss += __shfl_xor(ss, off, 64);
  }
  if ((t & 63) == 0) { red[(t >> 6) * 2] = s; red[(t >> 6) * 2 + 1] = ss; }
  __syncthreads();
  const float S = red[0] + red[2], SS = red[1] + red[3];
  const float mu = S * (1.f / 128.f);
  const float var = SS * (1.f / 128.f) - mu * mu;
  const float rstd = rsqrtf(var + EPSV);
  outU[g * 128 + t] = gg[t] * (h - mu) * rstd + gbt[t];
}

// ---------------- launch ----------------
extern "C" void kernel_launch(void* const* d_in, const int* in_sizes, int n_in,
                              void* d_out, int out_size, void* d_ws,
                              size_t ws_size, hipStream_t stream) {
  const float* x   = (const float*)d_in[0];
  const float* e   = (const float*)d_in[1];
  const float* u   = (const float*)d_in[2];
  const int* eidx  = (const int*)d_in[3];
  const int* batch = (const int*)d_in[4];
  const float* eW1 = (const float*)d_in[5];
  const float* eb1 = (const float*)d_in[6];
  const float* eW2 = (const float*)d_in[7];
  const float* eb2 = (const float*)d_in[8];
  const float* eg  = (const float*)d_in[9];
  const float* ebt = (const float*)d_in[10];
  const float* nW1 = (const float*)d_in[11];
  const float* nb1 = (const float*)d_in[12];
  const float* nW2 = (const float*)d_in[13];
  const float* nb2 = (const float*)d_in[14];
  const float* ng  = (const float*)d_in[15];
  const float* nbt = (const float*)d_in[16];
  const float* gW1 = (const float*)d_in[17];
  const float* gb1 = (const float*)d_in[18];
  const float* gW2 = (const float*)d_in[19];
  const float* gb2 = (const float*)d_in[20];
  const float* gg  = (const float*)d_in[21];
  const float* gbt = (const float*)d_in[22];

  char* ws = (char*)d_ws;
  float* e2g           = (float*)(ws + 0);
  float* n2g           = (float*)(ws + 32768);
  int*   cnt_r         = (int*)  (ws + 65536);
  int*   cnt_s         = (int*)  (ws + 265536);
  int*   offs_r        = (int*)  (ws + 465536);
  int*   cur_r         = (int*)  (ws + 665536);
  int*   offs_s        = (int*)  (ws + 865536);
  int*   cur_s         = (int*)  (ws + 1065536);
  int*   eidlist_r     = (int*)  (ws + 1265536);
  int*   eidlist_s     = (int*)  (ws + 4465536);
  int*   gs            = (int*)  (ws + 7665536);
  int*   posr          = (int*)  (ws + 10865536);
  int*   segidx        = (int*)  (ws + 14065536);
  unsigned short* xb   = (unsigned short*)(ws + 17265536);
  unsigned short* ub   = (unsigned short*)(ws + 30065536);
  unsigned short* W1eT = (unsigned short*)(ws + 30069632);
  unsigned short* WpqT = (unsigned short*)(ws + 30077824);
  unsigned short* eW2T = (unsigned short*)(ws + 30143360);
  unsigned short* nW1T = (unsigned short*)(ws + 30176128);
  unsigned short* nW2T = (unsigned short*)(ws + 30258048);
  unsigned short* PQ   = (unsigned short*)(ws + 30290816);
  float* Rg            = (float*)(ws + 55890816);
  unsigned short* e2b  = (unsigned short*)(ws + 55923584);  // 204,800,000 B
  const bool useB = ws_size >= (size_t)55923584 + 204800000;

  hipMemsetAsync(ws, 0, 465536, stream);

  const int* rowI = eidx;
  const int* colI = eidx + NE;

  cvt_pre_kernel<<<1024, 256, 0, stream>>>(x, xb, rowI, colI, cnt_r, cnt_s);
  cvt_small_kernel<<<472, 256, 0, stream>>>(u, eW1, eW2, nW1, nW2, ub, W1eT,
                                            WpqT, eW2T, nW1T, nW2T, Rg);
  pq_kernel<<<(NN + 63) / 64, 256, 0, stream>>>(xb, WpqT, PQ);

  float* outX = (float*)d_out;
  float* outE = outX + (size_t)NN * 128;
  float* outU = outE + (size_t)NE * 128;

  scan2_kernel<<<2, 1024, 0, stream>>>(cnt_r, offs_r, cur_r,
                                       cnt_s, offs_s, cur_s);
  fill_both_kernel<<<(NE + 255) / 256, 256, 0, stream>>>(
      rowI, colI, batch, cur_r, cur_s, posr, eidlist_r, eidlist_s, gs, segidx);

  edge_kernel<<<NE / 64, 256, 0, stream>>>(e, PQ, Rg, rowI, colI, batch, posr,
                                           W1eT, eW2T, eb1, eb2, eg, ebt,
                                           outE, useB ? e2b : nullptr);
  if (useB) {
    post_kernel<1><<<SEGB + (NN + 63) / 64, 256, 0, stream>>>(
        outE, e2b, segidx, gs, e2g,
        xb, ub, batch, offs_r, cnt_r, eidlist_r,
        nW1T, nW2T, nb1, nb2, ng, nbt, outX, n2g);
  } else {
    post_kernel<0><<<SEGB + (NN + 63) / 64, 256, 0, stream>>>(
        outE, e2b, eidlist_s, gs, e2g,
        xb, ub, batch, offs_r, cnt_r, eidlist_r,
        nW1T, nW2T, nb1, nb2, ng, nbt, outX, n2g);
  }
  glob_kernel<<<NG, 128, 0, stream>>>(u, n2g, e2g, gW1, gb1, gW2, gb2, gg, gbt,
                                      outU);
}